// Round 5
// baseline (282.164 us; speedup 1.0000x reference)
//
#include <hip/hip_runtime.h>
#include <hip/hip_bf16.h>
#include <hip/hip_fp16.h>

typedef unsigned short u16;
typedef __attribute__((ext_vector_type(8))) _Float16 f16x8;  // 8 fp16 = 4 VGPR
typedef __attribute__((ext_vector_type(4))) float f32x4;     // MFMA 16x16 acc

#define B_ 8
#define S_ 2048
#define H_ 1024
#define M_ (B_ * S_)   // 16384

__device__ __forceinline__ u16 f2h(float f) {
  _Float16 h = (_Float16)f;
  return __builtin_bit_cast(u16, h);
}

// ---------- convert fp32 -> fp16 ----------
__global__ void f32_to_f16_kernel(const float* __restrict__ x,
                                  u16* __restrict__ o, int n4) {
  int stride = gridDim.x * blockDim.x;
  for (int i = blockIdx.x * blockDim.x + threadIdx.x; i < n4; i += stride) {
    float4 v = reinterpret_cast<const float4*>(x)[i];
    ushort4 h;
    h.x = f2h(v.x); h.y = f2h(v.y); h.z = f2h(v.z); h.w = f2h(v.w);
    reinterpret_cast<ushort4*>(o)[i] = h;
  }
}

// ---------- transpose X fp32 [b][s][h] -> XT fp16 [b][h][s] ----------
__global__ void transpose_f32_kernel(const float* __restrict__ x,
                                     u16* __restrict__ xt) {
  __shared__ u16 t[64][65];
  int b = blockIdx.z, s0 = blockIdx.x * 64, h0 = blockIdx.y * 64;
  int tx = threadIdx.x, ty = threadIdx.y;
  const float* src = x + ((size_t)b * S_ + s0) * H_ + h0;
#pragma unroll
  for (int i = 0; i < 4; ++i)
    t[ty + 16 * i][tx] = f2h(src[(size_t)(ty + 16 * i) * H_ + tx]);
  __syncthreads();
  u16* dst = xt + ((size_t)b * H_ + h0) * S_ + s0;
#pragma unroll
  for (int i = 0; i < 4; ++i)
    dst[(size_t)(ty + 16 * i) * S_ + tx] = t[tx][ty + 16 * i];
}

// ---------- async global->LDS 16B ----------
__device__ __forceinline__ void async_stage16(const u16* g, u16* l) {
  __builtin_amdgcn_global_load_lds(
      (__attribute__((address_space(1))) void*)g,
      (__attribute__((address_space(3))) void*)l, 16, 0, 0);
}

// ---------- 256x256x64 8-phase fp16 BT-GEMM ------------------------------
// C[m,n] = sum_k A[m,k]*B[n,k], A/B row-major k-contiguous fp16.
// 512 thr / 8 waves (2M x 4N). LDS 2 slots x (A+B half-tiles) = 128 KB,
// XOR-swizzle byte^((row&7)<<4) on staging source + fragment reads.
// Counted vmcnt placed BEFORE the phase-closing barrier (all waves' loads
// retired before any wave's dependent ds_read).
// NEW r5: bijective XCD-aware workgroup swizzle (m204) — each XCD owns a
// contiguous chunk of the linear grid so blocks sharing A/B panels share L2.
template <int OM>  // 0: fp32 out; 1: fp16 out + bias
__global__ __launch_bounds__(512) void gemm8_kernel(
    const u16* __restrict__ A, const u16* __restrict__ B,
    float* __restrict__ Cf, u16* __restrict__ Ch,
    const float* __restrict__ bias,
    int lda, int ldb, int ldc, int K,
    long sAz, long sBz, long sCz) {
  __shared__ __align__(16) u16 sA[2][256 * 64];
  __shared__ __align__(16) u16 sB[2][256 * 64];

  // ---- XCD swizzle (T1, bijective m204) ----
  int gx = gridDim.x, gy = gridDim.y;
  int nwg = gx * gy * gridDim.z;
  int wgid = blockIdx.x + gx * (blockIdx.y + gy * blockIdx.z);
  int q = nwg >> 3, r = nwg & 7;
  int xcd = wgid & 7, idx = wgid >> 3;
  int nid = (xcd < r ? xcd * (q + 1) : r * (q + 1) + (xcd - r) * q) + idx;
  int bxi = nid % gx, t2 = nid / gx;
  int byi = t2 % gy, bzi = t2 / gy;

  int tid = threadIdx.x, wave = tid >> 6, lane = tid & 63;
  int wm = wave >> 2, wn = wave & 3;
  int bm = bxi * 256, bn = byi * 256;
  long zA = (long)bzi * sAz;
  long zB = (long)bzi * sBz;
  long zC = (long)bzi * sCz;
  const u16* gA = A + zA + (size_t)bm * lda;
  const u16* gB = B + zB + (size_t)bn * ldb;

  // staging constants: thread -> (row srow/srow+64, byte col scolb) of a half
  int srow = tid >> 3;             // 0..63
  int scolb = (tid & 7) << 4;      // 0..112
  int sco = (scolb ^ ((srow & 7) << 4)) >> 1;  // swizzled src col (u16)
  size_t aO0 = (size_t)srow * lda + sco, aO1 = aO0 + (size_t)64 * lda;
  size_t bO0 = (size_t)srow * ldb + sco, bO1 = bO0 + (size_t)64 * ldb;
  int ld0 = srow * 64 + (scolb >> 1), ld1 = ld0 + 64 * 64;

  auto stgA = [&](int slot, int half, int kofs) {
    const u16* g = gA + (size_t)(half * 128) * lda + kofs;
    u16* l = &sA[slot][half * 8192];
    async_stage16(g + aO0, l + ld0);
    async_stage16(g + aO1, l + ld1);
  };
  auto stgB = [&](int slot, int half, int kofs) {
    const u16* g = gB + (size_t)(half * 128) * ldb + kofs;
    u16* l = &sB[slot][half * 8192];
    async_stage16(g + bO0, l + ld0);
    async_stage16(g + bO1, l + ld1);
  };

  // fragment reads (swizzled)
  int la = lane & 15;
  int kg = (lane >> 4) << 4;
  auto frag = [&](const u16* base, int row, int colb) -> f16x8 {
    int off = (row << 7) + (colb ^ ((row & 7) << 4));
    return *reinterpret_cast<const f16x8*>(
        reinterpret_cast<const char*>(base) + off);
  };

  f16x8 aF[4][2], bF[2][2];
  f32x4 acc[8][4] = {};

  auto RA = [&](int slot, int qm) {
#pragma unroll
    for (int j = 0; j < 4; ++j)
#pragma unroll
      for (int ks = 0; ks < 2; ++ks)
        aF[j][ks] = frag(sA[slot], qm * 128 + (j * 2 + wm) * 16 + la,
                         ks * 64 + kg);
  };
  auto RB = [&](int slot, int qn) {
#pragma unroll
    for (int i = 0; i < 2; ++i)
#pragma unroll
      for (int ks = 0; ks < 2; ++ks)
        bF[i][ks] = frag(sB[slot], qn * 128 + (i * 4 + wn) * 16 + la,
                         ks * 64 + kg);
  };
  auto MM = [&](int qm, int qn) {
#pragma unroll
    for (int ks = 0; ks < 2; ++ks)
#pragma unroll
      for (int j = 0; j < 4; ++j)
#pragma unroll
        for (int i = 0; i < 2; ++i)
          acc[qm * 4 + j][qn * 2 + i] = __builtin_amdgcn_mfma_f32_16x16x32_f16(
              aF[j][ks], bF[i][ks], acc[qm * 4 + j][qn * 2 + i], 0, 0, 0);
  };

#define VM4 asm volatile("s_waitcnt vmcnt(4)" ::: "memory")
#define VM2 asm volatile("s_waitcnt vmcnt(2)" ::: "memory")
#define BAR __builtin_amdgcn_s_barrier()
#define LG0                                              \
  asm volatile("s_waitcnt lgkmcnt(0)" ::: "memory");     \
  __builtin_amdgcn_sched_barrier(0)
#define MFMA_CL(qm, qn)                 \
  __builtin_amdgcn_s_setprio(1);        \
  MM(qm, qn);                           \
  __builtin_amdgcn_s_setprio(0)

  // prologue: tile0 -> slot0 (A0,B0,A1,B1)
  stgA(0, 0, 0); stgB(0, 0, 0); stgA(0, 1, 0); stgB(0, 1, 0);
  VM4;   // retire A0,B0 (own); barrier makes it global
  BAR;

  int NI = K >> 7;  // iterations of 2 K-tiles
  for (int it = 0; it < NI; ++it) {
    int k1 = (2 * it + 1) << 6, k2 = (2 * it + 2) << 6;
    bool more = (it + 1 < NI);
    // ph1: q(0,0) slot0; stage A-half0 tile(2it+1)->slot1
    RA(0, 0); RB(0, 0); stgA(1, 0, k1);
    BAR; LG0; MFMA_CL(0, 0); VM2; BAR;
    // ph2: q(1,0); stage B-half0
    RA(0, 1); stgB(1, 0, k1);
    BAR; LG0; MFMA_CL(1, 0); BAR;
    // ph3: q(1,1); stage A-half1
    RB(0, 1); stgA(1, 1, k1);
    BAR; LG0; MFMA_CL(1, 1); BAR;
    // ph4: q(0,1); stage B-half1
    RA(0, 0); stgB(1, 1, k1);
    BAR; LG0; MFMA_CL(0, 1); VM4; BAR;
    // ph5: q(0,0) slot1; stage A-half0 tile(2it+2)->slot0
    RA(1, 0); RB(1, 0); if (more) stgA(0, 0, k2);
    BAR; LG0; MFMA_CL(0, 0); VM2; BAR;
    // ph6: q(1,0); stage B-half0
    RA(1, 1); if (more) stgB(0, 0, k2);
    BAR; LG0; MFMA_CL(1, 0); BAR;
    // ph7: q(1,1); stage A-half1
    RB(1, 1); if (more) stgA(0, 1, k2);
    BAR; LG0; MFMA_CL(1, 1); BAR;
    // ph8: q(0,1); stage B-half1
    RA(1, 0); if (more) stgB(0, 1, k2);
    BAR; LG0; MFMA_CL(0, 1); VM4; BAR;
  }
#undef VM4
#undef VM2
#undef BAR
#undef LG0
#undef MFMA_CL

  // Epilogue. C/D layout: col = lane&15, row = (lane>>4)*4 + reg.
#pragma unroll
  for (int mf = 0; mf < 8; ++mf) {
    int qm = mf >> 2, j = mf & 3;
    int row = bm + qm * 128 + (j * 2 + wm) * 16 + (lane >> 4) * 4;
#pragma unroll
    for (int nf = 0; nf < 4; ++nf) {
      int qn = nf >> 1, i = nf & 1;
      int col = bn + qn * 128 + (i * 4 + wn) * 16 + la;
#pragma unroll
      for (int r = 0; r < 4; ++r) {
        float v = acc[mf][nf][r];
        if constexpr (OM == 1) {
          Ch[zC + (size_t)(row + r) * ldc + col] = f2h(v + bias[col]);
        } else {
          Cf[zC + (size_t)(row + r) * ldc + col] = v;
        }
      }
    }
  }
}

// ---------- row softmax: fp32 [rows][2048] -> fp16 (pitch opitch u16) -----
__global__ __launch_bounds__(256) void softmax_kernel(const float* __restrict__ sc,
                                                      u16* __restrict__ attn,
                                                      int opitch) {
  __shared__ float red[4];
  size_t row = blockIdx.x;
  const float* p = sc + row * S_;
  u16* o = attn + row * (size_t)opitch;
  int t = threadIdx.x;
  float4 v0 = reinterpret_cast<const float4*>(p)[t];
  float4 v1 = reinterpret_cast<const float4*>(p)[t + 256];
  float mx = fmaxf(fmaxf(fmaxf(v0.x, v0.y), fmaxf(v0.z, v0.w)),
                   fmaxf(fmaxf(v1.x, v1.y), fmaxf(v1.z, v1.w)));
#pragma unroll
  for (int d = 32; d > 0; d >>= 1) mx = fmaxf(mx, __shfl_xor(mx, d));
  if ((t & 63) == 0) red[t >> 6] = mx;
  __syncthreads();
  mx = fmaxf(fmaxf(red[0], red[1]), fmaxf(red[2], red[3]));
  float e[8];
  e[0] = __expf(v0.x - mx); e[1] = __expf(v0.y - mx);
  e[2] = __expf(v0.z - mx); e[3] = __expf(v0.w - mx);
  e[4] = __expf(v1.x - mx); e[5] = __expf(v1.y - mx);
  e[6] = __expf(v1.z - mx); e[7] = __expf(v1.w - mx);
  float s = ((e[0] + e[1]) + (e[2] + e[3])) + ((e[4] + e[5]) + (e[6] + e[7]));
#pragma unroll
  for (int d = 32; d > 0; d >>= 1) s += __shfl_xor(s, d);
  __syncthreads();  // everyone done reading red (max phase)
  if ((t & 63) == 0) red[t >> 6] = s;
  __syncthreads();
  s = (red[0] + red[1]) + (red[2] + red[3]);
  float inv = 1.0f / s;
  ushort4 h0, h1;
  h0.x = f2h(e[0] * inv); h0.y = f2h(e[1] * inv);
  h0.z = f2h(e[2] * inv); h0.w = f2h(e[3] * inv);
  h1.x = f2h(e[4] * inv); h1.y = f2h(e[5] * inv);
  h1.z = f2h(e[6] * inv); h1.w = f2h(e[7] * inv);
  // all reads happened before the barriers above -> in-place safe
  reinterpret_cast<ushort4*>(o)[t] = h0;
  reinterpret_cast<ushort4*>(o)[t + 256] = h1;
}

extern "C" void kernel_launch(void* const* d_in, const int* in_sizes, int n_in,
                              void* d_out, int out_size, void* d_ws, size_t ws_size,
                              hipStream_t stream) {
  const float* X = (const float*)d_in[0];     // [8,2048,1024] fp32
  const float* W = (const float*)d_in[1];     // [1024,1024] fp32 (out,in)
  const float* bias = (const float*)d_in[2];  // [1024] fp32
  float* out = (float*)d_out;
  char* ws = (char*)d_ws;

  const size_t MB = 1ull << 20;
  u16* XF = (u16*)(ws);               // 32MB [16384][1024] fp16
  u16* WF = (u16*)(ws + 32 * MB);     // 2MB
  u16* XT = (u16*)(ws + 34 * MB);     // 32MB [b][1024][2048] fp16
  u16* QW = (u16*)(ws + 66 * MB);     // 32MB [16384][1024] fp16
  float* SC = (float*)(ws + 98 * MB); // CB*16MB fp32 scores
  u16* PF = (u16*)(ws + 162 * MB);    // 64MB full P (plan 2 only)

  // plan 2: CB=4 scores + dedicated full P, single full-GPU PV   (>=226MB)
  // plan 1: CB=4 scores + in-place P, PV per chunk               (>=163MB)
  // plan 0: CB=2 everything, in-place P                          (fallback)
  int plan = (ws_size >= 226 * MB) ? 2 : (ws_size >= 163 * MB) ? 1 : 0;
  int CB = (plan >= 1) ? 4 : 2;
  int nch = B_ / CB;

  // 1) X, W -> fp16
  f32_to_f16_kernel<<<2048, 256, 0, stream>>>(X, XF, M_ * H_ / 4);
  f32_to_f16_kernel<<<1024, 256, 0, stream>>>(W, WF, H_ * H_ / 4);
  // 2) XT[b][h][s] = fp16(X[b][s][h])
  transpose_f32_kernel<<<dim3(S_ / 64, H_ / 64, B_), dim3(64, 16), 0, stream>>>(X, XT);
  // 3) QW = X @ W^T + b -> fp16   (grid 64x4 = 256 blocks)
  gemm8_kernel<1><<<dim3(M_ / 256, H_ / 256, 1), 512, 0, stream>>>(
      XF, WF, nullptr, QW, bias, H_, H_, H_, H_, 0, 0, 0);
  // 4-6) per chunk: score -> softmax -> (PV)
  for (int ch = 0; ch < nch; ++ch) {
    long off = (long)ch * CB;
    gemm8_kernel<0><<<dim3(S_ / 256, S_ / 256, CB), 512, 0, stream>>>(
        QW + off * S_ * H_, XF + off * S_ * H_, SC, nullptr, nullptr,
        H_, H_, S_, H_, (long)S_ * H_, (long)S_ * H_, (long)S_ * S_);
    if (plan == 2) {
      softmax_kernel<<<CB * S_, 256, 0, stream>>>(
          SC, PF + off * S_ * S_, S_);
    } else {
      softmax_kernel<<<CB * S_, 256, 0, stream>>>(
          SC, (u16*)SC, 2 * S_);
      gemm8_kernel<0><<<dim3(S_ / 256, H_ / 256, CB), 512, 0, stream>>>(
          (u16*)SC, XT + off * (long)H_ * S_,
          out + off * (long)S_ * H_, nullptr, nullptr,
          2 * S_, S_, H_, S_, (long)S_ * 2 * S_, (long)H_ * S_, (long)S_ * H_);
    }
  }
  if (plan == 2) {
    // single full-GPU PV: grid 8x4x8 = 256 blocks
    gemm8_kernel<0><<<dim3(S_ / 256, H_ / 256, B_), 512, 0, stream>>>(
        PF, XT, out, nullptr, nullptr,
        S_, S_, H_, S_, (long)S_ * S_, (long)H_ * S_, (long)S_ * H_);
  }
}

// Round 6
// 265.607 us; speedup vs baseline: 1.0623x; 1.0623x over previous
//
#include <hip/hip_runtime.h>
#include <hip/hip_bf16.h>
#include <hip/hip_fp16.h>

typedef unsigned short u16;
typedef __attribute__((ext_vector_type(8))) _Float16 f16x8;  // 8 fp16 = 4 VGPR
typedef __attribute__((ext_vector_type(4))) float f32x4;     // MFMA 16x16 acc

#define B_ 8
#define S_ 2048
#define H_ 1024
#define M_ (B_ * S_)   // 16384

__device__ __forceinline__ u16 f2h(float f) {
  _Float16 h = (_Float16)f;
  return __builtin_bit_cast(u16, h);
}

// ---------- convert fp32 -> fp16 (W only) ----------
__global__ void f32_to_f16_kernel(const float* __restrict__ x,
                                  u16* __restrict__ o, int n4) {
  int stride = gridDim.x * blockDim.x;
  for (int i = blockIdx.x * blockDim.x + threadIdx.x; i < n4; i += stride) {
    float4 v = reinterpret_cast<const float4*>(x)[i];
    ushort4 h;
    h.x = f2h(v.x); h.y = f2h(v.y); h.z = f2h(v.z); h.w = f2h(v.w);
    reinterpret_cast<ushort4*>(o)[i] = h;
  }
}

// ---------- fused: X fp32 [b][s][h] -> XT fp16 [b][h][s] AND XF fp16 -------
__global__ void transpose_f32_kernel(const float* __restrict__ x,
                                     u16* __restrict__ xt,
                                     u16* __restrict__ xf) {
  __shared__ u16 t[64][65];
  int b = blockIdx.z, s0 = blockIdx.x * 64, h0 = blockIdx.y * 64;
  int tx = threadIdx.x, ty = threadIdx.y;
  const float* src = x + ((size_t)b * S_ + s0) * H_ + h0;
  u16* dstf = xf + ((size_t)b * S_ + s0) * H_ + h0;
#pragma unroll
  for (int i = 0; i < 4; ++i) {
    u16 h = f2h(src[(size_t)(ty + 16 * i) * H_ + tx]);
    t[ty + 16 * i][tx] = h;
    dstf[(size_t)(ty + 16 * i) * H_ + tx] = h;
  }
  __syncthreads();
  u16* dst = xt + ((size_t)b * H_ + h0) * S_ + s0;
#pragma unroll
  for (int i = 0; i < 4; ++i)
    dst[(size_t)(ty + 16 * i) * S_ + tx] = t[tx][ty + 16 * i];
}

// ---------- async global->LDS 16B ----------
__device__ __forceinline__ void async_stage16(const u16* g, u16* l) {
  __builtin_amdgcn_global_load_lds(
      (__attribute__((address_space(1))) void*)g,
      (__attribute__((address_space(3))) void*)l, 16, 0, 0);
}

// ---------- 256x256x64 8-phase fp16 BT-GEMM ------------------------------
// C[m,n] = sum_k A[m,k]*B[n,k], A/B row-major k-contiguous fp16.
// 512 thr / 8 waves (2M x 4N). LDS 2 slots x (A+B half-tiles) = 128 KB,
// XOR-swizzle byte^((row&7)<<4) on staging source + fragment reads.
// r6 schedule: per K-tile 4 phases, Gray quadrant order (0,0)->(0,1)->
// (1,1)->(1,0) (adjacent phases share one fragment set -> 28 wave-reads
// per K-tile, no deep reload). Next tile staged one half/phase in read
// order A0,B0,B1,A1; shallow counted vmcnt(4) at phases 1,2,4 only keeps
// >=2 halves in flight (never deep-drains). Waits precede the closing
// barrier so every wave's own loads are retired before any dependent
// ds_read behind the barrier.
template <int OM>  // 0: fp32 out; 1: fp16 out + bias
__global__ __launch_bounds__(512) void gemm8_kernel(
    const u16* __restrict__ A, const u16* __restrict__ B,
    float* __restrict__ Cf, u16* __restrict__ Ch,
    const float* __restrict__ bias,
    int lda, int ldb, int ldc, int K,
    long sAz, long sBz, long sCz) {
  __shared__ __align__(16) u16 sA[2][256 * 64];
  __shared__ __align__(16) u16 sB[2][256 * 64];

  // ---- XCD swizzle (T1, bijective m204) ----
  int gx = gridDim.x, gy = gridDim.y;
  int nwg = gx * gy * gridDim.z;
  int wgid = blockIdx.x + gx * (blockIdx.y + gy * blockIdx.z);
  int q = nwg >> 3, r = nwg & 7;
  int xcd = wgid & 7, idx = wgid >> 3;
  int nid = (xcd < r ? xcd * (q + 1) : r * (q + 1) + (xcd - r) * q) + idx;
  int bxi = nid % gx, t2 = nid / gx;
  int byi = t2 % gy, bzi = t2 / gy;

  int tid = threadIdx.x, wave = tid >> 6, lane = tid & 63;
  int wm = wave >> 2, wn = wave & 3;
  int bm = bxi * 256, bn = byi * 256;
  long zA = (long)bzi * sAz;
  long zB = (long)bzi * sBz;
  long zC = (long)bzi * sCz;
  const u16* gA = A + zA + (size_t)bm * lda;
  const u16* gB = B + zB + (size_t)bn * ldb;

  // staging constants: thread -> (row srow/srow+64, byte col scolb) of a half
  int srow = tid >> 3;             // 0..63
  int scolb = (tid & 7) << 4;      // 0..112
  int sco = (scolb ^ ((srow & 7) << 4)) >> 1;  // swizzled src col (u16)
  size_t aO0 = (size_t)srow * lda + sco, aO1 = aO0 + (size_t)64 * lda;
  size_t bO0 = (size_t)srow * ldb + sco, bO1 = bO0 + (size_t)64 * ldb;
  int ld0 = srow * 64 + (scolb >> 1), ld1 = ld0 + 64 * 64;

  auto stgA = [&](int slot, int half, int kofs) {
    const u16* g = gA + (size_t)(half * 128) * lda + kofs;
    u16* l = &sA[slot][half * 8192];
    async_stage16(g + aO0, l + ld0);
    async_stage16(g + aO1, l + ld1);
  };
  auto stgB = [&](int slot, int half, int kofs) {
    const u16* g = gB + (size_t)(half * 128) * ldb + kofs;
    u16* l = &sB[slot][half * 8192];
    async_stage16(g + bO0, l + ld0);
    async_stage16(g + bO1, l + ld1);
  };

  // fragment reads (swizzled)
  int la = lane & 15;
  int kg = (lane >> 4) << 4;
  auto frag = [&](const u16* base, int row, int colb) -> f16x8 {
    int off = (row << 7) + (colb ^ ((row & 7) << 4));
    return *reinterpret_cast<const f16x8*>(
        reinterpret_cast<const char*>(base) + off);
  };

  f16x8 aF[4][2], bF[2][2];
  f32x4 acc[8][4] = {};

  auto RA = [&](int slot, int qm) {
#pragma unroll
    for (int j = 0; j < 4; ++j)
#pragma unroll
      for (int ks = 0; ks < 2; ++ks)
        aF[j][ks] = frag(sA[slot], qm * 128 + (j * 2 + wm) * 16 + la,
                         ks * 64 + kg);
  };
  auto RB = [&](int slot, int qn) {
#pragma unroll
    for (int i = 0; i < 2; ++i)
#pragma unroll
      for (int ks = 0; ks < 2; ++ks)
        bF[i][ks] = frag(sB[slot], qn * 128 + (i * 4 + wn) * 16 + la,
                         ks * 64 + kg);
  };
  auto MM = [&](int qm, int qn) {
#pragma unroll
    for (int ks = 0; ks < 2; ++ks)
#pragma unroll
      for (int j = 0; j < 4; ++j)
#pragma unroll
        for (int i = 0; i < 2; ++i)
          acc[qm * 4 + j][qn * 2 + i] = __builtin_amdgcn_mfma_f32_16x16x32_f16(
              aF[j][ks], bF[i][ks], acc[qm * 4 + j][qn * 2 + i], 0, 0, 0);
  };

#define VM4 asm volatile("s_waitcnt vmcnt(4)" ::: "memory")
#define VM2 asm volatile("s_waitcnt vmcnt(2)" ::: "memory")
#define VM0 asm volatile("s_waitcnt vmcnt(0)" ::: "memory")
#define LG8 asm volatile("s_waitcnt lgkmcnt(8)" ::: "memory")
#define BAR __builtin_amdgcn_s_barrier()
#define LG0                                              \
  asm volatile("s_waitcnt lgkmcnt(0)" ::: "memory");     \
  __builtin_amdgcn_sched_barrier(0)
#define MFMA_CL(qm, qn)                 \
  __builtin_amdgcn_s_setprio(1);        \
  MM(qm, qn);                           \
  __builtin_amdgcn_s_setprio(0)

  // prologue: tile0 -> slot0, staged in read order A0,B0,B1,A1
  stgA(0, 0, 0); stgB(0, 0, 0); stgB(0, 1, 0); stgA(0, 1, 0);
  VM4;  // retire A0,B0; B1,A1 (4 loads) stay in flight
  BAR;

  int NT = K >> 6;  // K-tiles
  for (int t = 0; t < NT; ++t) {
    int s = t & 1, ns = s ^ 1;
    int kn = (t + 1) << 6;
    bool more = (t + 1 < NT);
    // ph1: q(0,0); stage next A0
    RA(s, 0); RB(s, 0);
    if (more) stgA(ns, 0, kn);
    LG8;
    BAR; LG0; MFMA_CL(0, 0);
    if (more) { VM4; } else { VM2; }   // retire current B1
    BAR;
    // ph2: q(0,1) — keep aF, read B1; stage next B0
    RB(s, 1);
    if (more) stgB(ns, 0, kn);
    BAR; LG0; MFMA_CL(0, 1);
    if (more) { VM4; } else { VM0; }   // retire current A1
    BAR;
    // ph3: q(1,1) — keep bF, read A1; stage next B1
    RA(s, 1);
    if (more) stgB(ns, 1, kn);
    BAR; LG0; MFMA_CL(1, 1);
    BAR;
    // ph4: q(1,0) — keep aF, re-read B0 (already resident); stage next A1
    RB(s, 0);
    if (more) stgA(ns, 1, kn);
    BAR; LG0; MFMA_CL(1, 0);
    if (more) { VM4; }                 // retire next A0,B0
    BAR;
  }
#undef VM4
#undef VM2
#undef VM0
#undef LG8
#undef BAR
#undef LG0
#undef MFMA_CL

  // Epilogue. C/D layout: col = lane&15, row = (lane>>4)*4 + reg.
#pragma unroll
  for (int mf = 0; mf < 8; ++mf) {
    int qm = mf >> 2, j = mf & 3;
    int row = bm + qm * 128 + (j * 2 + wm) * 16 + (lane >> 4) * 4;
#pragma unroll
    for (int nf = 0; nf < 4; ++nf) {
      int qn = nf >> 1, i = nf & 1;
      int col = bn + qn * 128 + (i * 4 + wn) * 16 + la;
#pragma unroll
      for (int r = 0; r < 4; ++r) {
        float v = acc[mf][nf][r];
        if constexpr (OM == 1) {
          Ch[zC + (size_t)(row + r) * ldc + col] = f2h(v + bias[col]);
        } else {
          Cf[zC + (size_t)(row + r) * ldc + col] = v;
        }
      }
    }
  }
}

// ---------- row softmax: fp32 [rows][2048] -> fp16 (pitch opitch u16) -----
__global__ __launch_bounds__(256) void softmax_kernel(const float* __restrict__ sc,
                                                      u16* __restrict__ attn,
                                                      int opitch) {
  __shared__ float red[4];
  size_t row = blockIdx.x;
  const float* p = sc + row * S_;
  u16* o = attn + row * (size_t)opitch;
  int t = threadIdx.x;
  float4 v0 = reinterpret_cast<const float4*>(p)[t];
  float4 v1 = reinterpret_cast<const float4*>(p)[t + 256];
  float mx = fmaxf(fmaxf(fmaxf(v0.x, v0.y), fmaxf(v0.z, v0.w)),
                   fmaxf(fmaxf(v1.x, v1.y), fmaxf(v1.z, v1.w)));
#pragma unroll
  for (int d = 32; d > 0; d >>= 1) mx = fmaxf(mx, __shfl_xor(mx, d));
  if ((t & 63) == 0) red[t >> 6] = mx;
  __syncthreads();
  mx = fmaxf(fmaxf(red[0], red[1]), fmaxf(red[2], red[3]));
  float e[8];
  e[0] = __expf(v0.x - mx); e[1] = __expf(v0.y - mx);
  e[2] = __expf(v0.z - mx); e[3] = __expf(v0.w - mx);
  e[4] = __expf(v1.x - mx); e[5] = __expf(v1.y - mx);
  e[6] = __expf(v1.z - mx); e[7] = __expf(v1.w - mx);
  float s = ((e[0] + e[1]) + (e[2] + e[3])) + ((e[4] + e[5]) + (e[6] + e[7]));
#pragma unroll
  for (int d = 32; d > 0; d >>= 1) s += __shfl_xor(s, d);
  __syncthreads();  // everyone done reading red (max phase)
  if ((t & 63) == 0) red[t >> 6] = s;
  __syncthreads();
  s = (red[0] + red[1]) + (red[2] + red[3]);
  float inv = 1.0f / s;
  ushort4 h0, h1;
  h0.x = f2h(e[0] * inv); h0.y = f2h(e[1] * inv);
  h0.z = f2h(e[2] * inv); h0.w = f2h(e[3] * inv);
  h1.x = f2h(e[4] * inv); h1.y = f2h(e[5] * inv);
  h1.z = f2h(e[6] * inv); h1.w = f2h(e[7] * inv);
  // all reads happened before the barriers above -> in-place safe
  reinterpret_cast<ushort4*>(o)[t] = h0;
  reinterpret_cast<ushort4*>(o)[t + 256] = h1;
}

extern "C" void kernel_launch(void* const* d_in, const int* in_sizes, int n_in,
                              void* d_out, int out_size, void* d_ws, size_t ws_size,
                              hipStream_t stream) {
  const float* X = (const float*)d_in[0];     // [8,2048,1024] fp32
  const float* W = (const float*)d_in[1];     // [1024,1024] fp32 (out,in)
  const float* bias = (const float*)d_in[2];  // [1024] fp32
  float* out = (float*)d_out;
  char* ws = (char*)d_ws;

  const size_t MB = 1ull << 20;
  u16* XF = (u16*)(ws);               // 32MB [16384][1024] fp16
  u16* WF = (u16*)(ws + 32 * MB);     // 2MB
  u16* XT = (u16*)(ws + 34 * MB);     // 32MB [b][1024][2048] fp16
  u16* QW = (u16*)(ws + 66 * MB);     // 32MB [16384][1024] fp16
  float* SC = (float*)(ws + 98 * MB); // CB*16MB fp32 scores
  u16* PF = (u16*)(ws + 162 * MB);    // 64MB full P (plan 2 only)

  // plan 2: CB=4 scores + dedicated full P, single full-GPU PV   (>=226MB)
  // plan 1: CB=4 scores + in-place P, PV per chunk               (>=163MB)
  // plan 0: CB=2 everything, in-place P                          (fallback)
  int plan = (ws_size >= 226 * MB) ? 2 : (ws_size >= 163 * MB) ? 1 : 0;
  int CB = (plan >= 1) ? 4 : 2;
  int nch = B_ / CB;

  // 1) W -> fp16
  f32_to_f16_kernel<<<1024, 256, 0, stream>>>(W, WF, H_ * H_ / 4);
  // 2) fused: XF = fp16(X); XT[b][h][s] = fp16(X[b][s][h])
  transpose_f32_kernel<<<dim3(S_ / 64, H_ / 64, B_), dim3(64, 16), 0, stream>>>(
      X, XT, XF);
  // 3) QW = X @ W^T + b -> fp16   (grid 64x4 = 256 blocks)
  gemm8_kernel<1><<<dim3(M_ / 256, H_ / 256, 1), 512, 0, stream>>>(
      XF, WF, nullptr, QW, bias, H_, H_, H_, H_, 0, 0, 0);
  // 4-6) per chunk: score -> softmax -> (PV)
  for (int ch = 0; ch < nch; ++ch) {
    long off = (long)ch * CB;
    gemm8_kernel<0><<<dim3(S_ / 256, S_ / 256, CB), 512, 0, stream>>>(
        QW + off * S_ * H_, XF + off * S_ * H_, SC, nullptr, nullptr,
        H_, H_, S_, H_, (long)S_ * H_, (long)S_ * H_, (long)S_ * S_);
    if (plan == 2) {
      softmax_kernel<<<CB * S_, 256, 0, stream>>>(
          SC, PF + off * S_ * S_, S_);
    } else {
      softmax_kernel<<<CB * S_, 256, 0, stream>>>(
          SC, (u16*)SC, 2 * S_);
      gemm8_kernel<0><<<dim3(S_ / 256, H_ / 256, CB), 512, 0, stream>>>(
          (u16*)SC, XT + off * (long)H_ * S_,
          out + off * (long)S_ * H_, nullptr, nullptr,
          2 * S_, S_, H_, S_, (long)S_ * 2 * S_, (long)H_ * S_, (long)S_ * H_);
    }
  }
  if (plan == 2) {
    // single full-GPU PV: grid 8x4x8 = 256 blocks
    gemm8_kernel<0><<<dim3(S_ / 256, H_ / 256, B_), 512, 0, stream>>>(
        PF, XT, out, nullptr, nullptr,
        S_, S_, H_, S_, (long)S_ * S_, (long)H_ * S_, (long)S_ * H_);
  }
}

// Round 8
// 257.308 us; speedup vs baseline: 1.0966x; 1.0323x over previous
//
#include <hip/hip_runtime.h>
#include <hip/hip_bf16.h>
#include <hip/hip_fp16.h>

typedef unsigned short u16;
typedef __attribute__((ext_vector_type(8))) _Float16 f16x8;  // 8 fp16 = 4 VGPR
typedef __attribute__((ext_vector_type(4))) float f32x4;     // MFMA 16x16 acc

#define B_ 8
#define S_ 2048
#define H_ 1024
#define M_ (B_ * S_)   // 16384

__device__ __forceinline__ u16 f2h(float f) {
  _Float16 h = (_Float16)f;
  return __builtin_bit_cast(u16, h);
}

// ---------- convert fp32 -> fp16 (W only) ----------
__global__ void f32_to_f16_kernel(const float* __restrict__ x,
                                  u16* __restrict__ o, int n4) {
  int stride = gridDim.x * blockDim.x;
  for (int i = blockIdx.x * blockDim.x + threadIdx.x; i < n4; i += stride) {
    float4 v = reinterpret_cast<const float4*>(x)[i];
    ushort4 h;
    h.x = f2h(v.x); h.y = f2h(v.y); h.z = f2h(v.z); h.w = f2h(v.w);
    reinterpret_cast<ushort4*>(o)[i] = h;
  }
}

// ---------- fused: X fp32 [b][s][h] -> XT fp16 [b][h][s] AND XF fp16 -------
__global__ void transpose_f32_kernel(const float* __restrict__ x,
                                     u16* __restrict__ xt,
                                     u16* __restrict__ xf) {
  __shared__ u16 t[64][65];
  int b = blockIdx.z, s0 = blockIdx.x * 64, h0 = blockIdx.y * 64;
  int tx = threadIdx.x, ty = threadIdx.y;
  const float* src = x + ((size_t)b * S_ + s0) * H_ + h0;
  u16* dstf = xf + ((size_t)b * S_ + s0) * H_ + h0;
#pragma unroll
  for (int i = 0; i < 4; ++i) {
    u16 h = f2h(src[(size_t)(ty + 16 * i) * H_ + tx]);
    t[ty + 16 * i][tx] = h;
    dstf[(size_t)(ty + 16 * i) * H_ + tx] = h;
  }
  __syncthreads();
  u16* dst = xt + ((size_t)b * H_ + h0) * S_ + s0;
#pragma unroll
  for (int i = 0; i < 4; ++i)
    dst[(size_t)(ty + 16 * i) * S_ + tx] = t[tx][ty + 16 * i];
}

// ---------- async global->LDS 16B ----------
__device__ __forceinline__ void async_stage16(const u16* g, u16* l) {
  __builtin_amdgcn_global_load_lds(
      (__attribute__((address_space(1))) void*)g,
      (__attribute__((address_space(3))) void*)l, 16, 0, 0);
}

// ---------- 256x256x64 8-phase fp16 BT-GEMM ------------------------------
// C[m,n] = sum_k A[m,k]*B[n,k], A/B row-major k-contiguous fp16.
// 512 thr / 8 waves (2M x 4N). LDS 2 slots x (A+B half-tiles) = 128 KB,
// XOR-swizzle byte^((row&7)<<4) on staging source + fragment reads.
//
// r8 ledger — EVERY stage targets a region whose last ds_read was drained
// (per-wave lgkmcnt(0)) before a BARRIER that precedes the DMA issue:
//   phase reads (Gray):  A0@ph1, B0@ph1+ph4, B1@ph2, A1@ph3   (slot s)
//   deaths:              A0 after ph1, B1 after ph2, A1 after ph3,
//                        B0 after ph4
//   stages: ph1: B0(T+1)->ns  [B0(ns) died ph4(t-1); barrier between]
//           ph2: A0(T+2)->s   [A0(s) died ph1(t);  barrier between]
//           ph3: B1(T+2)->s   [B1(s) died ph2(t);  barrier between]
//           ph4: A1(T+2)->s   [A1(s) died ph3(t);  barrier between]
// FIFO at end of ph4(t): [A0,B1,A1](T+1) + B0(T+1) + [A0,B1,A1](T+2)
// = 7 halves (14 loads). ONE vmcnt(6) per tile retires exactly tile T+1's
// four halves (distance 4-8 phases). Tail: VM0 at t==NT-2, none at NT-1.
// The wait precedes the closing barrier, so per-wave retirement + barrier
// = all-wave retirement.
template <int OM>  // 0: fp32 out; 1: fp16 out + bias
__global__ __launch_bounds__(512) void gemm8_kernel(
    const u16* __restrict__ A, const u16* __restrict__ B,
    float* __restrict__ Cf, u16* __restrict__ Ch,
    const float* __restrict__ bias,
    int lda, int ldb, int ldc, int K,
    long sAz, long sBz, long sCz) {
  __shared__ __align__(16) u16 sA[2][256 * 64];
  __shared__ __align__(16) u16 sB[2][256 * 64];

  // ---- XCD swizzle (T1, bijective m204) ----
  int gx = gridDim.x, gy = gridDim.y;
  int nwg = gx * gy * gridDim.z;
  int wgid = blockIdx.x + gx * (blockIdx.y + gy * blockIdx.z);
  int q = nwg >> 3, r = nwg & 7;
  int xcd = wgid & 7, idx = wgid >> 3;
  int nid = (xcd < r ? xcd * (q + 1) : r * (q + 1) + (xcd - r) * q) + idx;
  int bxi = nid % gx, t2 = nid / gx;
  int byi = t2 % gy, bzi = t2 / gy;

  int tid = threadIdx.x, wave = tid >> 6, lane = tid & 63;
  int wm = wave >> 2, wn = wave & 3;
  int bm = bxi * 256, bn = byi * 256;
  long zA = (long)bzi * sAz;
  long zB = (long)bzi * sBz;
  long zC = (long)bzi * sCz;
  const u16* gA = A + zA + (size_t)bm * lda;
  const u16* gB = B + zB + (size_t)bn * ldb;

  // staging constants: thread -> (row srow/srow+64, byte col scolb) of a half
  int srow = tid >> 3;             // 0..63
  int scolb = (tid & 7) << 4;      // 0..112
  int sco = (scolb ^ ((srow & 7) << 4)) >> 1;  // swizzled src col (u16)
  size_t aO0 = (size_t)srow * lda + sco, aO1 = aO0 + (size_t)64 * lda;
  size_t bO0 = (size_t)srow * ldb + sco, bO1 = bO0 + (size_t)64 * ldb;
  int ld0 = srow * 64 + (scolb >> 1), ld1 = ld0 + 64 * 64;

  auto stgA = [&](int slot, int half, int kofs) {
    const u16* g = gA + (size_t)(half * 128) * lda + kofs;
    u16* l = &sA[slot][half * 8192];
    async_stage16(g + aO0, l + ld0);
    async_stage16(g + aO1, l + ld1);
  };
  auto stgB = [&](int slot, int half, int kofs) {
    const u16* g = gB + (size_t)(half * 128) * ldb + kofs;
    u16* l = &sB[slot][half * 8192];
    async_stage16(g + bO0, l + ld0);
    async_stage16(g + bO1, l + ld1);
  };

  // fragment reads (swizzled)
  int la = lane & 15;
  int kg = (lane >> 4) << 4;
  auto frag = [&](const u16* base, int row, int colb) -> f16x8 {
    int off = (row << 7) + (colb ^ ((row & 7) << 4));
    return *reinterpret_cast<const f16x8*>(
        reinterpret_cast<const char*>(base) + off);
  };

  f16x8 aF[4][2], bF[2][2];
  f32x4 acc[8][4] = {};

  auto RA = [&](int slot, int qm) {
#pragma unroll
    for (int j = 0; j < 4; ++j)
#pragma unroll
      for (int ks = 0; ks < 2; ++ks)
        aF[j][ks] = frag(sA[slot], qm * 128 + (j * 2 + wm) * 16 + la,
                         ks * 64 + kg);
  };
  auto RB = [&](int slot, int qn) {
#pragma unroll
    for (int i = 0; i < 2; ++i)
#pragma unroll
      for (int ks = 0; ks < 2; ++ks)
        bF[i][ks] = frag(sB[slot], qn * 128 + (i * 4 + wn) * 16 + la,
                         ks * 64 + kg);
  };
  auto MM = [&](int qm, int qn) {
#pragma unroll
    for (int ks = 0; ks < 2; ++ks)
#pragma unroll
      for (int j = 0; j < 4; ++j)
#pragma unroll
        for (int i = 0; i < 2; ++i)
          acc[qm * 4 + j][qn * 2 + i] = __builtin_amdgcn_mfma_f32_16x16x32_f16(
              aF[j][ks], bF[i][ks], acc[qm * 4 + j][qn * 2 + i], 0, 0, 0);
  };

#define VM6 asm volatile("s_waitcnt vmcnt(6)" ::: "memory")
#define VM0 asm volatile("s_waitcnt vmcnt(0)" ::: "memory")
#define LG8 asm volatile("s_waitcnt lgkmcnt(8)" ::: "memory")
#define BAR __builtin_amdgcn_s_barrier()
#define LG0                                              \
  asm volatile("s_waitcnt lgkmcnt(0)" ::: "memory");     \
  __builtin_amdgcn_sched_barrier(0)
#define MFMA_CL(qm, qn)                 \
  __builtin_amdgcn_s_setprio(1);        \
  MM(qm, qn);                           \
  __builtin_amdgcn_s_setprio(0)

  int NT = K >> 6;  // K-tiles (16 or 32 here)
  // prologue: T0 (A0,B0,B1,A1) -> slot0; then T1's A0,B1,A1 -> slot1
  // (mimics steady-state FIFO: [A0,B1,A1](T+1) outstanding entering ph1).
  stgA(0, 0, 0); stgB(0, 0, 0); stgB(0, 1, 0); stgA(0, 1, 0);
  if (NT > 1) { stgA(1, 0, 64); stgB(1, 1, 64); stgA(1, 1, 64); }
  VM6;  // retire all 8 loads of T0; keep T1's 6
  BAR;

  for (int t = 0; t < NT; ++t) {
    int s = t & 1, ns = s ^ 1;
    int k1 = (t + 1) << 6, k2 = (t + 2) << 6;
    bool p1 = (t + 1 < NT), p2 = (t + 2 < NT);
    // ph1 q00: read A0,B0(s); stage B0(T+1)->ns (region dead since ph4(t-1))
    RA(s, 0); RB(s, 0);
    if (p1) stgB(ns, 0, k1);
    LG8;
    BAR; LG0; MFMA_CL(0, 0); BAR;
    // ph2 q01: read B1(s), keep aF; stage A0(T+2)->s (dead since ph1)
    RB(s, 1);
    if (p2) stgA(s, 0, k2);
    BAR; LG0; MFMA_CL(0, 1); BAR;
    // ph3 q11: read A1(s), keep bF; stage B1(T+2)->s (dead since ph2)
    RA(s, 1);
    if (p2) stgB(s, 1, k2);
    BAR; LG0; MFMA_CL(1, 1); BAR;
    // ph4 q10: read B0(s), keep aF; stage A1(T+2)->s (dead since ph3)
    RB(s, 0);
    if (p2) stgA(s, 1, k2);
    if (t < NT - 2) { VM6; } else if (t == NT - 2) { VM0; }
    BAR; LG0; MFMA_CL(1, 0); BAR;
  }
#undef VM6
#undef VM0
#undef LG8
#undef BAR
#undef LG0
#undef MFMA_CL

  // Epilogue. C/D layout: col = lane&15, row = (lane>>4)*4 + reg.
#pragma unroll
  for (int mf = 0; mf < 8; ++mf) {
    int qm = mf >> 2, j = mf & 3;
    int row = bm + qm * 128 + (j * 2 + wm) * 16 + (lane >> 4) * 4;
#pragma unroll
    for (int nf = 0; nf < 4; ++nf) {
      int qn = nf >> 1, i = nf & 1;
      int col = bn + qn * 128 + (i * 4 + wn) * 16 + la;
#pragma unroll
      for (int r = 0; r < 4; ++r) {
        float v = acc[mf][nf][r];
        if constexpr (OM == 1) {
          Ch[zC + (size_t)(row + r) * ldc + col] = f2h(v + bias[col]);
        } else {
          Cf[zC + (size_t)(row + r) * ldc + col] = v;
        }
      }
    }
  }
}

// ---------- row softmax: fp32 [rows][2048] -> fp16 (pitch opitch u16) -----
__global__ __launch_bounds__(256) void softmax_kernel(const float* __restrict__ sc,
                                                      u16* __restrict__ attn,
                                                      int opitch) {
  __shared__ float red[4];
  size_t row = blockIdx.x;
  const float* p = sc + row * S_;
  u16* o = attn + row * (size_t)opitch;
  int t = threadIdx.x;
  float4 v0 = reinterpret_cast<const float4*>(p)[t];
  float4 v1 = reinterpret_cast<const float4*>(p)[t + 256];
  float mx = fmaxf(fmaxf(fmaxf(v0.x, v0.y), fmaxf(v0.z, v0.w)),
                   fmaxf(fmaxf(v1.x, v1.y), fmaxf(v1.z, v1.w)));
#pragma unroll
  for (int d = 32; d > 0; d >>= 1) mx = fmaxf(mx, __shfl_xor(mx, d));
  if ((t & 63) == 0) red[t >> 6] = mx;
  __syncthreads();
  mx = fmaxf(fmaxf(red[0], red[1]), fmaxf(red[2], red[3]));
  float e[8];
  e[0] = __expf(v0.x - mx); e[1] = __expf(v0.y - mx);
  e[2] = __expf(v0.z - mx); e[3] = __expf(v0.w - mx);
  e[4] = __expf(v1.x - mx); e[5] = __expf(v1.y - mx);
  e[6] = __expf(v1.z - mx); e[7] = __expf(v1.w - mx);
  float s = ((e[0] + e[1]) + (e[2] + e[3])) + ((e[4] + e[5]) + (e[6] + e[7]));
#pragma unroll
  for (int d = 32; d > 0; d >>= 1) s += __shfl_xor(s, d);
  __syncthreads();  // everyone done reading red (max phase)
  if ((t & 63) == 0) red[t >> 6] = s;
  __syncthreads();
  s = (red[0] + red[1]) + (red[2] + red[3]);
  float inv = 1.0f / s;
  ushort4 h0, h1;
  h0.x = f2h(e[0] * inv); h0.y = f2h(e[1] * inv);
  h0.z = f2h(e[2] * inv); h0.w = f2h(e[3] * inv);
  h1.x = f2h(e[4] * inv); h1.y = f2h(e[5] * inv);
  h1.z = f2h(e[6] * inv); h1.w = f2h(e[7] * inv);
  // all reads happened before the barriers above -> in-place safe
  reinterpret_cast<ushort4*>(o)[t] = h0;
  reinterpret_cast<ushort4*>(o)[t + 256] = h1;
}

extern "C" void kernel_launch(void* const* d_in, const int* in_sizes, int n_in,
                              void* d_out, int out_size, void* d_ws, size_t ws_size,
                              hipStream_t stream) {
  const float* X = (const float*)d_in[0];     // [8,2048,1024] fp32
  const float* W = (const float*)d_in[1];     // [1024,1024] fp32 (out,in)
  const float* bias = (const float*)d_in[2];  // [1024] fp32
  float* out = (float*)d_out;
  char* ws = (char*)d_ws;

  const size_t MB = 1ull << 20;
  u16* XF = (u16*)(ws);               // 32MB [16384][1024] fp16
  u16* WF = (u16*)(ws + 32 * MB);     // 2MB
  u16* XT = (u16*)(ws + 34 * MB);     // 32MB [b][1024][2048] fp16
  u16* QW = (u16*)(ws + 66 * MB);     // 32MB [16384][1024] fp16
  float* SC = (float*)(ws + 98 * MB); // CB*16MB fp32 scores
  u16* PF = (u16*)(ws + 162 * MB);    // 64MB full P (plan 2 only)

  // plan 2: CB=4 scores + dedicated full P, single full-GPU PV   (>=226MB)
  // plan 1: CB=4 scores + in-place P, PV per chunk               (>=163MB)
  // plan 0: CB=2 everything, in-place P                          (fallback)
  int plan = (ws_size >= 226 * MB) ? 2 : (ws_size >= 163 * MB) ? 1 : 0;
  int CB = (plan >= 1) ? 4 : 2;
  int nch = B_ / CB;

  // 1) W -> fp16
  f32_to_f16_kernel<<<1024, 256, 0, stream>>>(W, WF, H_ * H_ / 4);
  // 2) fused: XF = fp16(X); XT[b][h][s] = fp16(X[b][s][h])
  transpose_f32_kernel<<<dim3(S_ / 64, H_ / 64, B_), dim3(64, 16), 0, stream>>>(
      X, XT, XF);
  // 3) QW = X @ W^T + b -> fp16   (grid 64x4 = 256 blocks)
  gemm8_kernel<1><<<dim3(M_ / 256, H_ / 256, 1), 512, 0, stream>>>(
      XF, WF, nullptr, QW, bias, H_, H_, H_, H_, 0, 0, 0);
  // 4-6) per chunk: score -> softmax -> (PV)
  for (int ch = 0; ch < nch; ++ch) {
    long off = (long)ch * CB;
    gemm8_kernel<0><<<dim3(S_ / 256, S_ / 256, CB), 512, 0, stream>>>(
        QW + off * S_ * H_, XF + off * S_ * H_, SC, nullptr, nullptr,
        H_, H_, S_, H_, (long)S_ * H_, (long)S_ * H_, (long)S_ * S_);
    if (plan == 2) {
      softmax_kernel<<<CB * S_, 256, 0, stream>>>(
          SC, PF + off * S_ * S_, S_);
    } else {
      softmax_kernel<<<CB * S_, 256, 0, stream>>>(
          SC, (u16*)SC, 2 * S_);
      gemm8_kernel<0><<<dim3(S_ / 256, H_ / 256, CB), 512, 0, stream>>>(
          (u16*)SC, XT + off * (long)H_ * S_,
          out + off * (long)S_ * H_, nullptr, nullptr,
          2 * S_, S_, H_, S_, (long)S_ * 2 * S_, (long)H_ * S_, (long)S_ * H_);
    }
  }
  if (plan == 2) {
    // single full-GPU PV: grid 8x4x8 = 256 blocks
    gemm8_kernel<0><<<dim3(S_ / 256, H_ / 256, B_), 512, 0, stream>>>(
        PF, XT, out, nullptr, nullptr,
        S_, S_, H_, S_, (long)S_ * S_, (long)H_ * S_, (long)S_ * H_);
  }
}